// Round 9
// baseline (1038.065 us; speedup 1.0000x reference)
//
#include <hip/hip_runtime.h>
#include <hip/hip_bf16.h>

// EdgeSHLayer: per-edge radial soft-one-hot (smooth_finite, 10 basis) + SH lmax=2.
// Outputs concatenated: [E*10] embed, then [E*9] sh, both f32.
//
// R9 (= R7/R8 resubmitted; both hit GPUAcquisitionTimeout) MEASUREMENT PROBE:
// internal REPEAT=4 loop around the edge_sh body (identical idempotent work
// each iteration). Purpose:
//   (a) dur_us delta / 3 = exact per-iteration kernel cost,
//   (b) the dispatch becomes long enough to surface in rocprof top-5 with
//       its own FETCH_SIZE/WRITE_SIZE/VALUBusy row (first direct evidence).
// Output is identical to the single-pass version.

#define TILE 256
#define REPEAT 4

typedef float nfloat4 __attribute__((ext_vector_type(4)));  // native 16B vector

__global__ __launch_bounds__(256) void pack_pos_kernel(
    const float* __restrict__ pos, float4* __restrict__ pos4, int N)
{
    int i = blockIdx.x * 256 + threadIdx.x;
    if (i < N) {
        pos4[i] = make_float4(pos[3 * i + 0], pos[3 * i + 1], pos[3 * i + 2], 0.0f);
    }
}

__global__ __launch_bounds__(TILE) void edge_sh_kernel(
    const int*    __restrict__ edge,   // [2, E] int32
    const float4* __restrict__ pos4,   // [N] packed
    const float*  __restrict__ radius, // [1]
    float*        __restrict__ out,    // [E*10 + E*9]
    int E)
{
    __shared__ __align__(16) float lds[TILE * 10 + TILE * 9]; // 19456 B -> 8 blk/CU
    float* lds_emb = lds;
    float* lds_sh  = lds + TILE * 10;

    const int tid = threadIdx.x;
    const long long base_e = (long long)blockIdx.x * TILE;
    const long long e = base_e + tid;
    const bool valid = (e < (long long)E);

    const float end = radius[0];
    const float inv_step = 11.0f / end;   // (NUM_BASIS+1)/end

    const long long rem_edges = (long long)E - base_e;
    const int n_emb4 = (int)((rem_edges >= TILE ? (long long)TILE * 10
                                                : rem_edges * 10) / 4);
    const int n_sh4  = (int)((rem_edges >= TILE ? (long long)TILE * 9
                                                : rem_edges * 9 ) / 4);

    #pragma unroll 1
    for (int rep = 0; rep < REPEAT; ++rep) {
        float vx = 0.0f, vy = 0.0f, vz = 0.0f;
        if (valid) {
            int s = __builtin_nontemporal_load(&edge[e]);
            int d = __builtin_nontemporal_load(&edge[(long long)E + e]);
            float4 a = pos4[s];
            float4 b = pos4[d];
            vx = b.x - a.x; vy = b.y - a.y; vz = b.z - a.z;
        }

        float len2 = vx * vx + vy * vy + vz * vz;
        float len  = sqrtf(len2);

        // ---- radial embedding: emb[j] = C * exp(-2/(1 - d^2)), d = len/step - (j+1)
        const float ls = len * inv_step;
        #pragma unroll
        for (int j = 0; j < 10; ++j) {
            float d = ls - (float)(j + 1);
            float t = __builtin_fmaf(-d, d, 1.0f);       // 1 - d^2
            float val = (t > 0.0f)
                      ? 26.669299714f * __expf(__fdividef(-2.0f, t))
                      : 0.0f;
            if (!valid) val = 0.0f;
            lds_emb[tid * 10 + j] = val;
        }

        // ---- spherical harmonics (lmax=2, 'norm', e3nn order)
        float inv = 1.0f / fmaxf(len, 1e-12f);
        float x = vx * inv, y = vy * inv, z = vz * inv;
        const float S3 = 1.7320508075688772f;
        lds_sh[tid * 9 + 0] = valid ? 1.0f : 0.0f;
        lds_sh[tid * 9 + 1] = x;
        lds_sh[tid * 9 + 2] = y;
        lds_sh[tid * 9 + 3] = z;
        lds_sh[tid * 9 + 4] = S3 * x * z;
        lds_sh[tid * 9 + 5] = S3 * x * y;
        lds_sh[tid * 9 + 6] = y * y - 0.5f * (x * x + z * z);
        lds_sh[tid * 9 + 7] = S3 * y * z;
        lds_sh[tid * 9 + 8] = 0.5f * S3 * (z * z - x * x);

        __syncthreads();

        // ---- coalesced 16B nt drain
        nfloat4* g_emb = (nfloat4*)(out + base_e * 10);
        const nfloat4* l_emb = (const nfloat4*)lds_emb;
        #pragma unroll
        for (int i = 0; i < 3; ++i) {
            int idx = tid + i * TILE;
            if (idx < n_emb4) __builtin_nontemporal_store(l_emb[idx], &g_emb[idx]);
        }

        nfloat4* g_sh = (nfloat4*)(out + (long long)E * 10 + base_e * 9);
        const nfloat4* l_sh = (const nfloat4*)lds_sh;
        #pragma unroll
        for (int i = 0; i < 3; ++i) {
            int idx = tid + i * TILE;
            if (idx < n_sh4) __builtin_nontemporal_store(l_sh[idx], &g_sh[idx]);
        }

        __syncthreads();   // iteration boundary (LDS reuse)
    }
}

extern "C" void kernel_launch(void* const* d_in, const int* in_sizes, int n_in,
                              void* d_out, int out_size, void* d_ws, size_t ws_size,
                              hipStream_t stream) {
    // inputs: 0=feature (UNUSED), 1=pos [N,3] f32, 2=max_neighbor_radius [1] f32,
    //         3=edge [2,E] int32
    const float* pos    = (const float*)d_in[1];
    const float* radius = (const float*)d_in[2];
    const int*   edge   = (const int*)d_in[3];
    float*       out    = (float*)d_out;

    const int N = in_sizes[1] / 3;
    const int E = in_sizes[3] / 2;

    float4* pos4 = (float4*)d_ws;   // N*16 B = 1.6 MB

    hipLaunchKernelGGL(pack_pos_kernel, dim3((N + 255) / 256), dim3(256), 0, stream,
                       pos, pos4, N);

    const int nblk = (E + TILE - 1) / TILE;
    hipLaunchKernelGGL(edge_sh_kernel, dim3(nblk), dim3(TILE), 0, stream,
                       edge, pos4, radius, out, E);
}